// Round 5
// baseline (2233.376 us; speedup 1.0000x reference)
//
#include <hip/hip_runtime.h>

static constexpr int KIN  = 25;
static constexpr int KOUT = 5;
static constexpr int NBLK = 128;      // blocks for hist/scatter
static constexpr int BSH  = 9;        // log2 nodes per bucket
static constexpr int NPB  = 1 << BSH; // 512 nodes per bucket
static constexpr int NBH  = 2048;     // hist row stride / max buckets

// ---------------------------------------------------------------------------
// k_node1: single-relation transforms (fallback layout).
// xl8: stride 8 (float4-aligned gathers). xr5: stride 5.
// ---------------------------------------------------------------------------
__global__ __launch_bounds__(256) void k_node1(
    const float* __restrict__ x,
    const float* __restrict__ Wl, const float* __restrict__ Wr,
    float* __restrict__ xl8, float* __restrict__ xr5, int n)
{
    __shared__ float sWl[KIN * KOUT];
    __shared__ float sWr[KIN * KOUT];
    __shared__ float sx[256 * KIN];

    const int tid = threadIdx.x;
    if (tid < KIN * KOUT) { sWl[tid] = Wl[tid]; sWr[tid] = Wr[tid]; }

    const int base = blockIdx.x * 256;
    const int cnt  = min(256, n - base);
    const size_t xbase = (size_t)base * KIN;
    for (int i = tid; i < cnt * KIN; i += 256) sx[i] = x[xbase + i];
    __syncthreads();

    if (tid >= cnt) return;
    const int node = base + tid;

    float xls[KOUT] = {0.f, 0.f, 0.f, 0.f, 0.f};
    float xrs[KOUT] = {0.f, 0.f, 0.f, 0.f, 0.f};
    const float* xp = &sx[tid * KIN];
#pragma unroll
    for (int i = 0; i < KIN; ++i) {
        const float xv = xp[i];
#pragma unroll
        for (int o = 0; o < KOUT; ++o) {
            xls[o] += xv * sWl[i * KOUT + o];
            xrs[o] += xv * sWr[i * KOUT + o];
        }
    }

    const size_t n8 = (size_t)node * 8;
    float4 v4;
    v4.x = xls[0]; v4.y = xls[1]; v4.z = xls[2]; v4.w = xls[3];
    *(float4*)(xl8 + n8) = v4;
    xl8[n8 + 4] = xls[4];
    const size_t n5 = (size_t)node * 5;
#pragma unroll
    for (int o = 0; o < KOUT; ++o) xr5[n5 + o] = xrs[o];
}

// ---------------------------------------------------------------------------
// k_node3: all three relations in one pass over x (reads x once).
// ---------------------------------------------------------------------------
__global__ __launch_bounds__(256) void k_node3(
    const float* __restrict__ x,
    const float* __restrict__ Wl0, const float* __restrict__ Wr0,
    const float* __restrict__ Wl1, const float* __restrict__ Wr1,
    const float* __restrict__ Wl2, const float* __restrict__ Wr2,
    float* __restrict__ xl8, float* __restrict__ xr5,  // [3][n][*]
    int n)
{
    __shared__ float sWl[3][KIN * KOUT];
    __shared__ float sWr[3][KIN * KOUT];
    __shared__ float sx[256 * KIN];

    const int tid = threadIdx.x;
    if (tid < KIN * KOUT) {
        sWl[0][tid] = Wl0[tid]; sWr[0][tid] = Wr0[tid];
        sWl[1][tid] = Wl1[tid]; sWr[1][tid] = Wr1[tid];
        sWl[2][tid] = Wl2[tid]; sWr[2][tid] = Wr2[tid];
    }

    const int base = blockIdx.x * 256;
    const int cnt  = min(256, n - base);
    const size_t xbase = (size_t)base * KIN;
    for (int i = tid; i < cnt * KIN; i += 256) sx[i] = x[xbase + i];
    __syncthreads();

    if (tid >= cnt) return;
    const int node = base + tid;

    float xls[3][KOUT] = {};
    float xrs[3][KOUT] = {};
    const float* xp = &sx[tid * KIN];
#pragma unroll
    for (int i = 0; i < KIN; ++i) {
        const float xv = xp[i];
#pragma unroll
        for (int r = 0; r < 3; ++r)
#pragma unroll
            for (int o = 0; o < KOUT; ++o) {
                xls[r][o] += xv * sWl[r][i * KOUT + o];
                xrs[r][o] += xv * sWr[r][i * KOUT + o];
            }
    }

#pragma unroll
    for (int r = 0; r < 3; ++r) {
        const size_t n8 = (size_t)r * n * 8 + (size_t)node * 8;
        float4 v4;
        v4.x = xls[r][0]; v4.y = xls[r][1]; v4.z = xls[r][2]; v4.w = xls[r][3];
        *(float4*)(xl8 + n8) = v4;
        xl8[n8 + 4] = xls[r][4];
        const size_t n5 = (size_t)r * n * 5 + (size_t)node * 5;
#pragma unroll
        for (int o = 0; o < KOUT; ++o) xr5[n5 + o] = xrs[r][o];
    }
}

// ---------------------------------------------------------------------------
// k_hist: per-block bucket histogram of dst (LDS atomics only).
// ---------------------------------------------------------------------------
__global__ __launch_bounds__(256) void k_hist(
    const int* __restrict__ dst, int E, int NB,
    int* __restrict__ hist_blk)
{
    __shared__ int h[NBH];
    const int b = blockIdx.x, tid = threadIdx.x;
    for (int i = tid; i < NB; i += 256) h[i] = 0;
    __syncthreads();
    const int chunk = (E + NBLK - 1) / NBLK;
    const int eb = b * chunk, ee = min(E, eb + chunk);
    for (int i = eb + tid; i < ee; i += 256)
        atomicAdd(&h[dst[i] >> BSH], 1);
    __syncthreads();
    for (int i = tid; i < NB; i += 256) hist_blk[b * NBH + i] = h[i];
}

// ---------------------------------------------------------------------------
// k_colsum: totals[i] = sum_b hist_blk[b][i]   (grid-parallel)
// ---------------------------------------------------------------------------
__global__ __launch_bounds__(256) void k_colsum(
    const int* __restrict__ hist_blk, int NB, int* __restrict__ totals)
{
    const int i = blockIdx.x * 256 + threadIdx.x;
    if (i >= NB) return;
    int s = 0;
    for (int b = 0; b < NBLK; ++b) s += hist_blk[b * NBH + i];
    totals[i] = s;
}

// ---------------------------------------------------------------------------
// k_scan2: exclusive scan of totals[0..NB) -> base/cursor. 2 elems/thread,
// handles NB <= 2048. base[i]=E for i>=NB (zero totals), sentinel included.
// ---------------------------------------------------------------------------
__global__ __launch_bounds__(1024) void k_scan2(
    const int* __restrict__ totals, int E, int NB,
    int* __restrict__ base, int* __restrict__ cursor)
{
    __shared__ int s[1024];
    const int t = threadIdx.x;
    const int i0 = 2 * t, i1 = 2 * t + 1;
    const int t0 = (i0 < NB) ? totals[i0] : 0;
    const int t1 = (i1 < NB) ? totals[i1] : 0;
    const int pair = t0 + t1;
    s[t] = pair;
    __syncthreads();
    for (int off = 1; off < 1024; off <<= 1) {
        int v = (t >= off) ? s[t - off] : 0;
        __syncthreads();
        s[t] += v;
        __syncthreads();
    }
    const int excl = s[t] - pair;
    base[i0] = excl;        cursor[i0] = excl;
    base[i1] = excl + t0;   cursor[i1] = excl + t0;
    if (t == 1023) base[2048] = E;
}

// ---------------------------------------------------------------------------
// k_scatter: reserve disjoint per-(block,bucket) ranges, scatter edges packed
// as (src << BSH) | (dst & (NPB-1)).
// ---------------------------------------------------------------------------
__global__ __launch_bounds__(256) void k_scatter(
    const int* __restrict__ src, const int* __restrict__ dst, int E, int NB,
    int* __restrict__ cursor, int* __restrict__ rs)
{
    __shared__ int h[NBH];
    __shared__ int cur[NBH];
    const int b = blockIdx.x, tid = threadIdx.x;
    for (int i = tid; i < NB; i += 256) h[i] = 0;
    __syncthreads();
    const int chunk = (E + NBLK - 1) / NBLK;
    const int eb = b * chunk, ee = min(E, eb + chunk);
    for (int i = eb + tid; i < ee; i += 256)
        atomicAdd(&h[dst[i] >> BSH], 1);
    __syncthreads();
    for (int i = tid; i < NB; i += 256)
        cur[i] = (h[i] > 0) ? atomicAdd(&cursor[i], h[i]) : 0;
    __syncthreads();
    for (int i = eb + tid; i < ee; i += 256) {
        const int d = dst[i];
        const int bkt = d >> BSH;
        const int pos = atomicAdd(&cur[bkt], 1);          // LDS atomic
        rs[pos] = (src[i] << BSH) | (d & (NPB - 1));
    }
}

// ---------------------------------------------------------------------------
// k_gather: one block per bucket, LDS acc[512][6] (12 KB -> 8 blocks/CU).
// Epilogue folds self-loop + bias + LeakyReLU(0.1), writes xout.
// ---------------------------------------------------------------------------
__global__ __launch_bounds__(256) void k_gather(
    const int* __restrict__ rs, const int* __restrict__ base,
    const float* __restrict__ xl8, const float* __restrict__ xr5,
    const float* __restrict__ att, const float* __restrict__ bias,
    float* __restrict__ xout, int n)
{
    __shared__ float acc[NPB][6];
    const int bkt = blockIdx.x, tid = threadIdx.x;
    for (int i = tid; i < NPB * 6; i += 256) ((float*)acc)[i] = 0.f;

    const float a0 = att[0], a1 = att[1], a2 = att[2], a3 = att[3], a4 = att[4];
    const int node0 = bkt << BSH;
    __syncthreads();

    const int eb = base[bkt], ee = base[bkt + 1];
    for (int i = eb + tid; i < ee; i += 256) {
        const int v  = rs[i];
        const int s  = v >> BSH;
        const int dl = v & (NPB - 1);

        const size_t s8 = (size_t)s * 8;
        const float4 xs = *(const float4*)(xl8 + s8);
        const float  xs4 = xl8[s8 + 4];
        const size_t d5 = (size_t)(node0 + dl) * 5;

        float t, logit = 0.f;
        t = xs.x + xr5[d5 + 0]; t = (t >= 0.f) ? t : 0.2f * t; logit += t * a0;
        t = xs.y + xr5[d5 + 1]; t = (t >= 0.f) ? t : 0.2f * t; logit += t * a1;
        t = xs.z + xr5[d5 + 2]; t = (t >= 0.f) ? t : 0.2f * t; logit += t * a2;
        t = xs.w + xr5[d5 + 3]; t = (t >= 0.f) ? t : 0.2f * t; logit += t * a3;
        t = xs4  + xr5[d5 + 4]; t = (t >= 0.f) ? t : 0.2f * t; logit += t * a4;

        const float w = __expf(logit);
        atomicAdd(&acc[dl][0], w * xs.x);
        atomicAdd(&acc[dl][1], w * xs.y);
        atomicAdd(&acc[dl][2], w * xs.z);
        atomicAdd(&acc[dl][3], w * xs.w);
        atomicAdd(&acc[dl][4], w * xs4);
        atomicAdd(&acc[dl][5], w);
    }
    __syncthreads();

    const float b0 = bias[0], b1 = bias[1], b2 = bias[2], b3 = bias[3], b4 = bias[4];
    for (int l = tid; l < NPB; l += 256) {
        const int node = node0 + l;
        if (node >= n) break;
        const size_t s8 = (size_t)node * 8;
        const float4 xs = *(const float4*)(xl8 + s8);
        const float  xs4 = xl8[s8 + 4];
        const size_t d5 = (size_t)node * 5;

        float t, logit = 0.f;                 // self-loop logit
        t = xs.x + xr5[d5 + 0]; t = (t >= 0.f) ? t : 0.2f * t; logit += t * a0;
        t = xs.y + xr5[d5 + 1]; t = (t >= 0.f) ? t : 0.2f * t; logit += t * a1;
        t = xs.z + xr5[d5 + 2]; t = (t >= 0.f) ? t : 0.2f * t; logit += t * a2;
        t = xs.w + xr5[d5 + 3]; t = (t >= 0.f) ? t : 0.2f * t; logit += t * a3;
        t = xs4  + xr5[d5 + 4]; t = (t >= 0.f) ? t : 0.2f * t; logit += t * a4;
        const float w = __expf(logit);

        const float inv = 1.0f / (acc[l][5] + w);
        float v;
        v = (acc[l][0] + w * xs.x) * inv + b0; xout[d5 + 0] = (v >= 0.f) ? v : 0.1f * v;
        v = (acc[l][1] + w * xs.y) * inv + b1; xout[d5 + 1] = (v >= 0.f) ? v : 0.1f * v;
        v = (acc[l][2] + w * xs.z) * inv + b2; xout[d5 + 2] = (v >= 0.f) ? v : 0.1f * v;
        v = (acc[l][3] + w * xs.w) * inv + b3; xout[d5 + 3] = (v >= 0.f) ? v : 0.1f * v;
        v = (acc[l][4] + w * xs4 ) * inv + b4; xout[d5 + 4] = (v >= 0.f) ? v : 0.1f * v;
    }
}

// ---------------------------------------------------------------------------
// k_mlp: fused projection + classifier.
// ---------------------------------------------------------------------------
__global__ __launch_bounds__(256) void k_mlp(
    const float* __restrict__ xp, const float* __restrict__ xs,
    const float* __restrict__ xv,
    const float* __restrict__ Wp1, const float* __restrict__ bp1,
    const float* __restrict__ Wp2, const float* __restrict__ bp2,
    const float* __restrict__ Wc1, const float* __restrict__ bc1,
    const float* __restrict__ Wc2, const float* __restrict__ bc2,
    float* __restrict__ out, int n)
{
    __shared__ float sW[257];
    const int tid = threadIdx.x;
    if (tid < 150) sW[tid] = Wp1[tid];
    if (tid < 10)  sW[150 + tid] = bp1[tid];
    if (tid < 50)  sW[160 + tid] = Wp2[tid];
    if (tid < 5)   sW[210 + tid] = bp2[tid];
    if (tid < 25)  sW[215 + tid] = Wc1[tid];
    if (tid < 5)   sW[240 + tid] = bc1[tid];
    if (tid < 10)  sW[245 + tid] = Wc2[tid];
    if (tid < 2)   sW[255 + tid] = bc2[tid];
    __syncthreads();

    const int node = blockIdx.x * 256 + tid;
    if (node >= n) return;
    const size_t n5 = (size_t)node * KOUT;

    float h[15];
#pragma unroll
    for (int k = 0; k < 5; ++k) {
        h[k]      = xp[n5 + k];
        h[5 + k]  = xs[n5 + k];
        h[10 + k] = xv[n5 + k];
    }

    float t1[10];
#pragma unroll
    for (int o = 0; o < 10; ++o) {
        float a = sW[150 + o];
#pragma unroll
        for (int i = 0; i < 15; ++i) a += h[i] * sW[i * 10 + o];
        t1[o] = (a >= 0.f) ? a : 0.1f * a;
    }

    float t2[5];
#pragma unroll
    for (int o = 0; o < 5; ++o) {
        float a = sW[210 + o];
#pragma unroll
        for (int i = 0; i < 10; ++i) a += t1[i] * sW[160 + i * 5 + o];
        t2[o] = a;
    }

    float t3[5];
#pragma unroll
    for (int o = 0; o < 5; ++o) {
        float a = sW[240 + o];
#pragma unroll
        for (int i = 0; i < 5; ++i) a += t2[i] * sW[215 + i * 5 + o];
        t3[o] = (a >= 0.f) ? a : 0.1f * a;
    }

    float o0 = sW[255], o1 = sW[256];
#pragma unroll
    for (int i = 0; i < 5; ++i) {
        o0 += t3[i] * sW[245 + i * 2 + 0];
        o1 += t3[i] * sW[245 + i * 2 + 1];
    }
    out[(size_t)node * 2 + 0] = o0;
    out[(size_t)node * 2 + 1] = o1;
}

// ---------------------------------------------------------------------------
extern "C" void kernel_launch(void* const* d_in, const int* in_sizes, int n_in,
                              void* d_out, int out_size, void* d_ws, size_t ws_size,
                              hipStream_t stream)
{
    const float* x = (const float*)d_in[0];
    const int n = in_sizes[0] / KIN;          // 1,000,000
    const int E = in_sizes[1] / 2;            // 8,000,000
    const int NB = (n + NPB - 1) >> BSH;      // 1954 buckets (needs n <= 2^20)

    const int* ei[3] = { (const int*)d_in[1], (const int*)d_in[2], (const int*)d_in[3] };
    const float *Wl[3], *Wr[3], *att[3], *bias[3];
    for (int r = 0; r < 3; ++r) {
        const int base = 4 + r * 4;
        Wl[r]   = (const float*)d_in[base + 0];
        Wr[r]   = (const float*)d_in[base + 1];
        att[r]  = (const float*)d_in[base + 2];
        bias[r] = (const float*)d_in[base + 3];
    }
    const float* Wp1 = (const float*)d_in[16];
    const float* bp1 = (const float*)d_in[17];
    const float* Wp2 = (const float*)d_in[18];
    const float* bp2 = (const float*)d_in[19];
    const float* Wc1 = (const float*)d_in[20];
    const float* bc1 = (const float*)d_in[21];
    const float* Wc2 = (const float*)d_in[22];
    const float* bc2 = (const float*)d_in[23];

    // ws layouts (floats first, then ints):
    //   B (proven ~146MB): xout[15n] | xl8[8n] | xr5[5n] | ints
    //   A (~250MB):        xout[15n] | xl8[3][8n] | xr5[3][5n] | ints
    //   ints: rs[E] | hist_blk[NBLK*NBH] | totals[NBH] | base[NBH+1] | cursor[NBH]
    const size_t ints_need = (size_t)E + (size_t)NBLK * NBH + 3 * NBH + 1;
    const size_t need_A = ((size_t)54 * n + ints_need) * 4;
    const bool bigws = ws_size >= need_A;

    float* ws   = (float*)d_ws;
    float* xout = ws;
    float* xl8  = ws + (size_t)15 * n;
    float* xr5  = xl8 + (bigws ? (size_t)24 * n : (size_t)8 * n);
    int*   rs   = (int*)(xr5 + (bigws ? (size_t)15 * n : (size_t)5 * n));
    int*   hist_blk = rs + (size_t)E;
    int*   totals   = hist_blk + (size_t)NBLK * NBH;
    int*   base     = totals + NBH;
    int*   cursor   = base + NBH + 1;

    const int nb_node = (n + 255) / 256;
    const int nb_cols = (NB + 255) / 256;

    if (bigws) {
        k_node3<<<nb_node, 256, 0, stream>>>(x, Wl[0], Wr[0], Wl[1], Wr[1],
                                             Wl[2], Wr[2], xl8, xr5, n);
    }

    for (int r = 0; r < 3; ++r) {
        float* xo = xout + (size_t)r * 5 * n;
        const int* src = ei[r];
        const int* dst = ei[r] + E;
        float* xl_r = bigws ? (xl8 + (size_t)r * 8 * n) : xl8;
        float* xr_r = bigws ? (xr5 + (size_t)r * 5 * n) : xr5;

        if (!bigws)
            k_node1<<<nb_node, 256, 0, stream>>>(x, Wl[r], Wr[r], xl_r, xr_r, n);

        k_hist   <<<NBLK,    256,  0, stream>>>(dst, E, NB, hist_blk);
        k_colsum <<<nb_cols, 256,  0, stream>>>(hist_blk, NB, totals);
        k_scan2  <<<1,       1024, 0, stream>>>(totals, E, NB, base, cursor);
        k_scatter<<<NBLK,    256,  0, stream>>>(src, dst, E, NB, cursor, rs);
        k_gather <<<NB,      256,  0, stream>>>(rs, base, xl_r, xr_r,
                                                att[r], bias[r], xo, n);
    }

    k_mlp<<<nb_node, 256, 0, stream>>>(xout, xout + (size_t)5 * n, xout + (size_t)10 * n,
                                       Wp1, bp1, Wp2, bp2, Wc1, bc1, Wc2, bc2,
                                       (float*)d_out, n);
}

// Round 6
// 1448.030 us; speedup vs baseline: 1.5424x; 1.5424x over previous
//
#include <hip/hip_runtime.h>

static constexpr int KIN  = 25;
static constexpr int KOUT = 5;
static constexpr int NBLK = 512;      // blocks for hist/scatter
static constexpr int BTH  = 1024;     // threads for hist/scatter
static constexpr int BSH  = 9;        // log2 nodes per bucket
static constexpr int NPB  = 1 << BSH; // 512 nodes per bucket
static constexpr int NBH  = 2048;     // hist row stride / max buckets

// ---------------------------------------------------------------------------
// k_node1: single-relation transforms (fallback layout).
// ---------------------------------------------------------------------------
__global__ __launch_bounds__(256) void k_node1(
    const float* __restrict__ x,
    const float* __restrict__ Wl, const float* __restrict__ Wr,
    float* __restrict__ xl8, float* __restrict__ xr5, int n)
{
    __shared__ float sWl[KIN * KOUT];
    __shared__ float sWr[KIN * KOUT];
    __shared__ float sx[256 * KIN];

    const int tid = threadIdx.x;
    if (tid < KIN * KOUT) { sWl[tid] = Wl[tid]; sWr[tid] = Wr[tid]; }

    const int base = blockIdx.x * 256;
    const int cnt  = min(256, n - base);
    const size_t xbase = (size_t)base * KIN;
    for (int i = tid; i < cnt * KIN; i += 256) sx[i] = x[xbase + i];
    __syncthreads();

    if (tid >= cnt) return;
    const int node = base + tid;

    float xls[KOUT] = {0.f, 0.f, 0.f, 0.f, 0.f};
    float xrs[KOUT] = {0.f, 0.f, 0.f, 0.f, 0.f};
    const float* xp = &sx[tid * KIN];
#pragma unroll
    for (int i = 0; i < KIN; ++i) {
        const float xv = xp[i];
#pragma unroll
        for (int o = 0; o < KOUT; ++o) {
            xls[o] += xv * sWl[i * KOUT + o];
            xrs[o] += xv * sWr[i * KOUT + o];
        }
    }

    const size_t n8 = (size_t)node * 8;
    float4 v4;
    v4.x = xls[0]; v4.y = xls[1]; v4.z = xls[2]; v4.w = xls[3];
    *(float4*)(xl8 + n8) = v4;
    xl8[n8 + 4] = xls[4];
    const size_t n5 = (size_t)node * 5;
#pragma unroll
    for (int o = 0; o < KOUT; ++o) xr5[n5 + o] = xrs[o];
}

// ---------------------------------------------------------------------------
// k_node3: all three relations in one pass over x.
// ---------------------------------------------------------------------------
__global__ __launch_bounds__(256) void k_node3(
    const float* __restrict__ x,
    const float* __restrict__ Wl0, const float* __restrict__ Wr0,
    const float* __restrict__ Wl1, const float* __restrict__ Wr1,
    const float* __restrict__ Wl2, const float* __restrict__ Wr2,
    float* __restrict__ xl8, float* __restrict__ xr5,  // [3][n][*]
    int n)
{
    __shared__ float sWl[3][KIN * KOUT];
    __shared__ float sWr[3][KIN * KOUT];
    __shared__ float sx[256 * KIN];

    const int tid = threadIdx.x;
    if (tid < KIN * KOUT) {
        sWl[0][tid] = Wl0[tid]; sWr[0][tid] = Wr0[tid];
        sWl[1][tid] = Wl1[tid]; sWr[1][tid] = Wr1[tid];
        sWl[2][tid] = Wl2[tid]; sWr[2][tid] = Wr2[tid];
    }

    const int base = blockIdx.x * 256;
    const int cnt  = min(256, n - base);
    const size_t xbase = (size_t)base * KIN;
    for (int i = tid; i < cnt * KIN; i += 256) sx[i] = x[xbase + i];
    __syncthreads();

    if (tid >= cnt) return;
    const int node = base + tid;

    float xls[3][KOUT] = {};
    float xrs[3][KOUT] = {};
    const float* xp = &sx[tid * KIN];
#pragma unroll
    for (int i = 0; i < KIN; ++i) {
        const float xv = xp[i];
#pragma unroll
        for (int r = 0; r < 3; ++r)
#pragma unroll
            for (int o = 0; o < KOUT; ++o) {
                xls[r][o] += xv * sWl[r][i * KOUT + o];
                xrs[r][o] += xv * sWr[r][i * KOUT + o];
            }
    }

#pragma unroll
    for (int r = 0; r < 3; ++r) {
        const size_t n8 = (size_t)r * n * 8 + (size_t)node * 8;
        float4 v4;
        v4.x = xls[r][0]; v4.y = xls[r][1]; v4.z = xls[r][2]; v4.w = xls[r][3];
        *(float4*)(xl8 + n8) = v4;
        xl8[n8 + 4] = xls[r][4];
        const size_t n5 = (size_t)r * n * 5 + (size_t)node * 5;
#pragma unroll
        for (int o = 0; o < KOUT; ++o) xr5[n5 + o] = xrs[r][o];
    }
}

// ---------------------------------------------------------------------------
// k_hist: per-block bucket histogram of dst (LDS atomics only).
// ---------------------------------------------------------------------------
__global__ __launch_bounds__(BTH) void k_hist(
    const int* __restrict__ dst, int E, int NB,
    int* __restrict__ hist_blk)
{
    __shared__ int h[NBH];
    const int b = blockIdx.x, tid = threadIdx.x;
    for (int i = tid; i < NB; i += BTH) h[i] = 0;
    __syncthreads();
    const int chunk = (E + NBLK - 1) / NBLK;
    const int eb = b * chunk, ee = min(E, eb + chunk);
    for (int i = eb + tid; i < ee; i += BTH)
        atomicAdd(&h[dst[i] >> BSH], 1);
    __syncthreads();
    for (int i = tid; i < NB; i += BTH) hist_blk[b * NBH + i] = h[i];
}

// ---------------------------------------------------------------------------
// k_sumoffs: per bucket i, turn hist_blk[b][i] IN PLACE into the exclusive
// prefix over blocks (relative offset of block b inside bucket i), and write
// totals[i]. Coalesced: fixed b, consecutive i are contiguous.
// ---------------------------------------------------------------------------
__global__ __launch_bounds__(256) void k_sumoffs(
    int* __restrict__ hist_blk, int NB, int* __restrict__ totals)
{
    const int i = blockIdx.x * 256 + threadIdx.x;
    if (i >= NB) return;
    int s = 0;
    for (int b = 0; b < NBLK; ++b) {
        const int t = hist_blk[b * NBH + i];
        hist_blk[b * NBH + i] = s;
        s += t;
    }
    totals[i] = s;
}

// ---------------------------------------------------------------------------
// k_scan2: exclusive scan of totals[0..NB) -> base. 2 elems/thread, NB<=2048.
// ---------------------------------------------------------------------------
__global__ __launch_bounds__(1024) void k_scan2(
    const int* __restrict__ totals, int E, int NB,
    int* __restrict__ base)
{
    __shared__ int s[1024];
    const int t = threadIdx.x;
    const int i0 = 2 * t, i1 = 2 * t + 1;
    const int t0 = (i0 < NB) ? totals[i0] : 0;
    const int t1 = (i1 < NB) ? totals[i1] : 0;
    const int pair = t0 + t1;
    s[t] = pair;
    __syncthreads();
    for (int off = 1; off < 1024; off <<= 1) {
        int v = (t >= off) ? s[t - off] : 0;
        __syncthreads();
        s[t] += v;
        __syncthreads();
    }
    const int excl = s[t] - pair;
    base[i0] = excl;
    base[i1] = excl + t0;
    if (t == 1023) base[2048] = E;
}

// ---------------------------------------------------------------------------
// k_scatter: single pass. cur[i] = base[i] + blkoff[b][i] (precomputed, no
// global atomics), then LDS-atomic local positions; scatter packed edges.
// ---------------------------------------------------------------------------
__global__ __launch_bounds__(BTH) void k_scatter(
    const int* __restrict__ src, const int* __restrict__ dst, int E, int NB,
    const int* __restrict__ hist_blk, const int* __restrict__ base,
    int* __restrict__ rs)
{
    __shared__ int cur[NBH];
    const int b = blockIdx.x, tid = threadIdx.x;
    for (int i = tid; i < NB; i += BTH)
        cur[i] = base[i] + hist_blk[b * NBH + i];
    __syncthreads();
    const int chunk = (E + NBLK - 1) / NBLK;
    const int eb = b * chunk, ee = min(E, eb + chunk);
    for (int i = eb + tid; i < ee; i += BTH) {
        const int d = dst[i];
        const int bkt = d >> BSH;
        const int pos = atomicAdd(&cur[bkt], 1);          // LDS atomic
        rs[pos] = (src[i] << BSH) | (d & (NPB - 1));
    }
}

// ---------------------------------------------------------------------------
// k_gather: one block per bucket, LDS acc[512][6] (12 KB). Epilogue folds
// self-loop + bias + LeakyReLU(0.1), writes xout.
// ---------------------------------------------------------------------------
__global__ __launch_bounds__(256) void k_gather(
    const int* __restrict__ rs, const int* __restrict__ base,
    const float* __restrict__ xl8, const float* __restrict__ xr5,
    const float* __restrict__ att, const float* __restrict__ bias,
    float* __restrict__ xout, int n)
{
    __shared__ float acc[NPB][6];
    const int bkt = blockIdx.x, tid = threadIdx.x;
    for (int i = tid; i < NPB * 6; i += 256) ((float*)acc)[i] = 0.f;

    const float a0 = att[0], a1 = att[1], a2 = att[2], a3 = att[3], a4 = att[4];
    const int node0 = bkt << BSH;
    __syncthreads();

    const int eb = base[bkt], ee = base[bkt + 1];
    for (int i = eb + tid; i < ee; i += 256) {
        const int v  = rs[i];
        const int s  = v >> BSH;
        const int dl = v & (NPB - 1);

        const size_t s8 = (size_t)s * 8;
        const float4 xs = *(const float4*)(xl8 + s8);
        const float  xs4 = xl8[s8 + 4];
        const size_t d5 = (size_t)(node0 + dl) * 5;

        float t, logit = 0.f;
        t = xs.x + xr5[d5 + 0]; t = (t >= 0.f) ? t : 0.2f * t; logit += t * a0;
        t = xs.y + xr5[d5 + 1]; t = (t >= 0.f) ? t : 0.2f * t; logit += t * a1;
        t = xs.z + xr5[d5 + 2]; t = (t >= 0.f) ? t : 0.2f * t; logit += t * a2;
        t = xs.w + xr5[d5 + 3]; t = (t >= 0.f) ? t : 0.2f * t; logit += t * a3;
        t = xs4  + xr5[d5 + 4]; t = (t >= 0.f) ? t : 0.2f * t; logit += t * a4;

        const float w = __expf(logit);
        atomicAdd(&acc[dl][0], w * xs.x);
        atomicAdd(&acc[dl][1], w * xs.y);
        atomicAdd(&acc[dl][2], w * xs.z);
        atomicAdd(&acc[dl][3], w * xs.w);
        atomicAdd(&acc[dl][4], w * xs4);
        atomicAdd(&acc[dl][5], w);
    }
    __syncthreads();

    const float b0 = bias[0], b1 = bias[1], b2 = bias[2], b3 = bias[3], b4 = bias[4];
    for (int l = tid; l < NPB; l += 256) {
        const int node = node0 + l;
        if (node >= n) break;
        const size_t s8 = (size_t)node * 8;
        const float4 xs = *(const float4*)(xl8 + s8);
        const float  xs4 = xl8[s8 + 4];
        const size_t d5 = (size_t)node * 5;

        float t, logit = 0.f;                 // self-loop logit
        t = xs.x + xr5[d5 + 0]; t = (t >= 0.f) ? t : 0.2f * t; logit += t * a0;
        t = xs.y + xr5[d5 + 1]; t = (t >= 0.f) ? t : 0.2f * t; logit += t * a1;
        t = xs.z + xr5[d5 + 2]; t = (t >= 0.f) ? t : 0.2f * t; logit += t * a2;
        t = xs.w + xr5[d5 + 3]; t = (t >= 0.f) ? t : 0.2f * t; logit += t * a3;
        t = xs4  + xr5[d5 + 4]; t = (t >= 0.f) ? t : 0.2f * t; logit += t * a4;
        const float w = __expf(logit);

        const float inv = 1.0f / (acc[l][5] + w);
        float v;
        v = (acc[l][0] + w * xs.x) * inv + b0; xout[d5 + 0] = (v >= 0.f) ? v : 0.1f * v;
        v = (acc[l][1] + w * xs.y) * inv + b1; xout[d5 + 1] = (v >= 0.f) ? v : 0.1f * v;
        v = (acc[l][2] + w * xs.z) * inv + b2; xout[d5 + 2] = (v >= 0.f) ? v : 0.1f * v;
        v = (acc[l][3] + w * xs.w) * inv + b3; xout[d5 + 3] = (v >= 0.f) ? v : 0.1f * v;
        v = (acc[l][4] + w * xs4 ) * inv + b4; xout[d5 + 4] = (v >= 0.f) ? v : 0.1f * v;
    }
}

// ---------------------------------------------------------------------------
// k_mlp: fused projection + classifier.
// ---------------------------------------------------------------------------
__global__ __launch_bounds__(256) void k_mlp(
    const float* __restrict__ xp, const float* __restrict__ xs,
    const float* __restrict__ xv,
    const float* __restrict__ Wp1, const float* __restrict__ bp1,
    const float* __restrict__ Wp2, const float* __restrict__ bp2,
    const float* __restrict__ Wc1, const float* __restrict__ bc1,
    const float* __restrict__ Wc2, const float* __restrict__ bc2,
    float* __restrict__ out, int n)
{
    __shared__ float sW[257];
    const int tid = threadIdx.x;
    if (tid < 150) sW[tid] = Wp1[tid];
    if (tid < 10)  sW[150 + tid] = bp1[tid];
    if (tid < 50)  sW[160 + tid] = Wp2[tid];
    if (tid < 5)   sW[210 + tid] = bp2[tid];
    if (tid < 25)  sW[215 + tid] = Wc1[tid];
    if (tid < 5)   sW[240 + tid] = bc1[tid];
    if (tid < 10)  sW[245 + tid] = Wc2[tid];
    if (tid < 2)   sW[255 + tid] = bc2[tid];
    __syncthreads();

    const int node = blockIdx.x * 256 + tid;
    if (node >= n) return;
    const size_t n5 = (size_t)node * KOUT;

    float h[15];
#pragma unroll
    for (int k = 0; k < 5; ++k) {
        h[k]      = xp[n5 + k];
        h[5 + k]  = xs[n5 + k];
        h[10 + k] = xv[n5 + k];
    }

    float t1[10];
#pragma unroll
    for (int o = 0; o < 10; ++o) {
        float a = sW[150 + o];
#pragma unroll
        for (int i = 0; i < 15; ++i) a += h[i] * sW[i * 10 + o];
        t1[o] = (a >= 0.f) ? a : 0.1f * a;
    }

    float t2[5];
#pragma unroll
    for (int o = 0; o < 5; ++o) {
        float a = sW[210 + o];
#pragma unroll
        for (int i = 0; i < 10; ++i) a += t1[i] * sW[160 + i * 5 + o];
        t2[o] = a;
    }

    float t3[5];
#pragma unroll
    for (int o = 0; o < 5; ++o) {
        float a = sW[240 + o];
#pragma unroll
        for (int i = 0; i < 5; ++i) a += t2[i] * sW[215 + i * 5 + o];
        t3[o] = (a >= 0.f) ? a : 0.1f * a;
    }

    float o0 = sW[255], o1 = sW[256];
#pragma unroll
    for (int i = 0; i < 5; ++i) {
        o0 += t3[i] * sW[245 + i * 2 + 0];
        o1 += t3[i] * sW[245 + i * 2 + 1];
    }
    out[(size_t)node * 2 + 0] = o0;
    out[(size_t)node * 2 + 1] = o1;
}

// ---------------------------------------------------------------------------
extern "C" void kernel_launch(void* const* d_in, const int* in_sizes, int n_in,
                              void* d_out, int out_size, void* d_ws, size_t ws_size,
                              hipStream_t stream)
{
    const float* x = (const float*)d_in[0];
    const int n = in_sizes[0] / KIN;          // 1,000,000
    const int E = in_sizes[1] / 2;            // 8,000,000
    const int NB = (n + NPB - 1) >> BSH;      // 1954 buckets (needs n <= 2^20)

    const int* ei[3] = { (const int*)d_in[1], (const int*)d_in[2], (const int*)d_in[3] };
    const float *Wl[3], *Wr[3], *att[3], *bias[3];
    for (int r = 0; r < 3; ++r) {
        const int base = 4 + r * 4;
        Wl[r]   = (const float*)d_in[base + 0];
        Wr[r]   = (const float*)d_in[base + 1];
        att[r]  = (const float*)d_in[base + 2];
        bias[r] = (const float*)d_in[base + 3];
    }
    const float* Wp1 = (const float*)d_in[16];
    const float* bp1 = (const float*)d_in[17];
    const float* Wp2 = (const float*)d_in[18];
    const float* bp2 = (const float*)d_in[19];
    const float* Wc1 = (const float*)d_in[20];
    const float* bc1 = (const float*)d_in[21];
    const float* Wc2 = (const float*)d_in[22];
    const float* bc2 = (const float*)d_in[23];

    // ws layouts (floats then ints):
    //   B (~144MB): xout[15n] | xl8[8n] | xr5[5n] | rs[E] | totals | base
    //   A (~248MB): xout[15n] | xl8[3][8n] | xr5[3][5n] | rs[E] | totals | base
    // hist_blk (NBLK*NBH ints = 4MB) OVERLAYS xout[10n..15n) (the xv slice):
    // it is dead before the last k_gather writes that slice (same stream,
    // strict ordering), and only k_mlp reads xout afterwards.
    const size_t ints_need = (size_t)E + NBH + NBH + 1;
    const size_t need_A = ((size_t)54 * n + ints_need) * 4;
    const bool bigws = ws_size >= need_A;

    float* ws   = (float*)d_ws;
    float* xout = ws;
    float* xl8  = ws + (size_t)15 * n;
    float* xr5  = xl8 + (bigws ? (size_t)24 * n : (size_t)8 * n);
    int*   rs   = (int*)(xr5 + (bigws ? (size_t)15 * n : (size_t)5 * n));
    int*   totals   = rs + (size_t)E;
    int*   base     = totals + NBH;
    int*   hist_blk = (int*)(xout + (size_t)10 * n);   // overlay on xv slice

    const int nb_node = (n + 255) / 256;
    const int nb_cols = (NB + 255) / 256;

    if (bigws) {
        k_node3<<<nb_node, 256, 0, stream>>>(x, Wl[0], Wr[0], Wl[1], Wr[1],
                                             Wl[2], Wr[2], xl8, xr5, n);
    }

    for (int r = 0; r < 3; ++r) {
        float* xo = xout + (size_t)r * 5 * n;
        const int* src = ei[r];
        const int* dst = ei[r] + E;
        float* xl_r = bigws ? (xl8 + (size_t)r * 8 * n) : xl8;
        float* xr_r = bigws ? (xr5 + (size_t)r * 5 * n) : xr5;

        if (!bigws)
            k_node1<<<nb_node, 256, 0, stream>>>(x, Wl[r], Wr[r], xl_r, xr_r, n);

        k_hist   <<<NBLK,    BTH,  0, stream>>>(dst, E, NB, hist_blk);
        k_sumoffs<<<nb_cols, 256,  0, stream>>>(hist_blk, NB, totals);
        k_scan2  <<<1,       1024, 0, stream>>>(totals, E, NB, base);
        k_scatter<<<NBLK,    BTH,  0, stream>>>(src, dst, E, NB, hist_blk, base, rs);
        k_gather <<<NB,      256,  0, stream>>>(rs, base, xl_r, xr_r,
                                                att[r], bias[r], xo, n);
    }

    k_mlp<<<nb_node, 256, 0, stream>>>(xout, xout + (size_t)5 * n, xout + (size_t)10 * n,
                                       Wp1, bp1, Wp2, bp2, Wc1, bc1, Wc2, bc2,
                                       (float*)d_out, n);
}

// Round 7
// 1389.414 us; speedup vs baseline: 1.6074x; 1.0422x over previous
//
#include <hip/hip_runtime.h>

static constexpr int KIN  = 25;
static constexpr int KOUT = 5;
static constexpr int NBLK = 512;      // blocks for hist/scatter
static constexpr int BTH  = 1024;     // threads for hist/scatter
static constexpr int BSH  = 9;        // log2 nodes per bucket
static constexpr int NPB  = 1 << BSH; // 512 nodes per bucket
static constexpr int NBH  = 2048;     // hist row stride / max buckets
static constexpr int BROW = NBH + 1;  // base row stride (incl. sentinel)

// ---------------------------------------------------------------------------
// k_node1: single-relation transforms (fallback layout).
// ---------------------------------------------------------------------------
__global__ __launch_bounds__(256) void k_node1(
    const float* __restrict__ x,
    const float* __restrict__ Wl, const float* __restrict__ Wr,
    float* __restrict__ xl8, float* __restrict__ xr5, int n)
{
    __shared__ float sWl[KIN * KOUT];
    __shared__ float sWr[KIN * KOUT];
    __shared__ float sx[256 * KIN];

    const int tid = threadIdx.x;
    if (tid < KIN * KOUT) { sWl[tid] = Wl[tid]; sWr[tid] = Wr[tid]; }

    const int base = blockIdx.x * 256;
    const int cnt  = min(256, n - base);
    const size_t xbase = (size_t)base * KIN;
    for (int i = tid; i < cnt * KIN; i += 256) sx[i] = x[xbase + i];
    __syncthreads();

    if (tid >= cnt) return;
    const int node = base + tid;

    float xls[KOUT] = {0.f, 0.f, 0.f, 0.f, 0.f};
    float xrs[KOUT] = {0.f, 0.f, 0.f, 0.f, 0.f};
    const float* xp = &sx[tid * KIN];
#pragma unroll
    for (int i = 0; i < KIN; ++i) {
        const float xv = xp[i];
#pragma unroll
        for (int o = 0; o < KOUT; ++o) {
            xls[o] += xv * sWl[i * KOUT + o];
            xrs[o] += xv * sWr[i * KOUT + o];
        }
    }

    const size_t n8 = (size_t)node * 8;
    float4 v4;
    v4.x = xls[0]; v4.y = xls[1]; v4.z = xls[2]; v4.w = xls[3];
    *(float4*)(xl8 + n8) = v4;
    xl8[n8 + 4] = xls[4];
    const size_t n5 = (size_t)node * 5;
#pragma unroll
    for (int o = 0; o < KOUT; ++o) xr5[n5 + o] = xrs[o];
}

// ---------------------------------------------------------------------------
// k_node3: all three relations in one pass over x.
// ---------------------------------------------------------------------------
__global__ __launch_bounds__(256) void k_node3(
    const float* __restrict__ x,
    const float* __restrict__ Wl0, const float* __restrict__ Wr0,
    const float* __restrict__ Wl1, const float* __restrict__ Wr1,
    const float* __restrict__ Wl2, const float* __restrict__ Wr2,
    float* __restrict__ xl8, float* __restrict__ xr5,  // [3][n][*]
    int n)
{
    __shared__ float sWl[3][KIN * KOUT];
    __shared__ float sWr[3][KIN * KOUT];
    __shared__ float sx[256 * KIN];

    const int tid = threadIdx.x;
    if (tid < KIN * KOUT) {
        sWl[0][tid] = Wl0[tid]; sWr[0][tid] = Wr0[tid];
        sWl[1][tid] = Wl1[tid]; sWr[1][tid] = Wr1[tid];
        sWl[2][tid] = Wl2[tid]; sWr[2][tid] = Wr2[tid];
    }

    const int base = blockIdx.x * 256;
    const int cnt  = min(256, n - base);
    const size_t xbase = (size_t)base * KIN;
    for (int i = tid; i < cnt * KIN; i += 256) sx[i] = x[xbase + i];
    __syncthreads();

    if (tid >= cnt) return;
    const int node = base + tid;

    float xls[3][KOUT] = {};
    float xrs[3][KOUT] = {};
    const float* xp = &sx[tid * KIN];
#pragma unroll
    for (int i = 0; i < KIN; ++i) {
        const float xv = xp[i];
#pragma unroll
        for (int r = 0; r < 3; ++r)
#pragma unroll
            for (int o = 0; o < KOUT; ++o) {
                xls[r][o] += xv * sWl[r][i * KOUT + o];
                xrs[r][o] += xv * sWr[r][i * KOUT + o];
            }
    }

#pragma unroll
    for (int r = 0; r < 3; ++r) {
        const size_t n8 = (size_t)r * n * 8 + (size_t)node * 8;
        float4 v4;
        v4.x = xls[r][0]; v4.y = xls[r][1]; v4.z = xls[r][2]; v4.w = xls[r][3];
        *(float4*)(xl8 + n8) = v4;
        xl8[n8 + 4] = xls[r][4];
        const size_t n5 = (size_t)r * n * 5 + (size_t)node * 5;
#pragma unroll
        for (int o = 0; o < KOUT; ++o) xr5[n5 + o] = xrs[r][o];
    }
}

// ---------------------------------------------------------------------------
// k_hist3: per-block bucket histogram of dst. blockIdx.y = relation.
// ---------------------------------------------------------------------------
__global__ __launch_bounds__(BTH) void k_hist3(
    const int* __restrict__ d0p, const int* __restrict__ d1p,
    const int* __restrict__ d2p, int E, int NB, int* __restrict__ hist3)
{
    __shared__ int h[NBH];
    const int rel = blockIdx.y, b = blockIdx.x, tid = threadIdx.x;
    const int* dst = (rel == 0) ? d0p : (rel == 1 ? d1p : d2p);
    int* hist_blk = hist3 + (size_t)rel * NBLK * NBH;

    for (int i = tid; i < NB; i += BTH) h[i] = 0;
    __syncthreads();
    const int chunk = (E + NBLK - 1) / NBLK;
    const int eb = b * chunk, ee = min(E, eb + chunk);
    for (int i = eb + tid; i < ee; i += BTH)
        atomicAdd(&h[dst[i] >> BSH], 1);
    __syncthreads();
    for (int i = tid; i < NB; i += BTH) hist_blk[b * NBH + i] = h[i];
}

// ---------------------------------------------------------------------------
// k_sumoffs3: per bucket, turn hist rows in place into exclusive per-block
// offsets; write bucket totals. blockIdx.y = relation.
// ---------------------------------------------------------------------------
__global__ __launch_bounds__(256) void k_sumoffs3(
    int* __restrict__ hist3, int NB, int* __restrict__ totals3)
{
    const int rel = blockIdx.y;
    int* hist_blk = hist3 + (size_t)rel * NBLK * NBH;
    int* totals   = totals3 + rel * NBH;
    const int i = blockIdx.x * 256 + threadIdx.x;
    if (i >= NB) return;
    int s = 0;
    for (int b = 0; b < NBLK; ++b) {
        const int t = hist_blk[b * NBH + i];
        hist_blk[b * NBH + i] = s;
        s += t;
    }
    totals[i] = s;
}

// ---------------------------------------------------------------------------
// k_scan3: exclusive scan of totals -> base per relation. blockIdx.x = rel.
// ---------------------------------------------------------------------------
__global__ __launch_bounds__(1024) void k_scan3(
    const int* __restrict__ totals3, int E, int NB, int* __restrict__ base3)
{
    __shared__ int s[1024];
    const int rel = blockIdx.x;
    const int* totals = totals3 + rel * NBH;
    int* base = base3 + rel * BROW;

    const int t = threadIdx.x;
    const int i0 = 2 * t, i1 = 2 * t + 1;
    const int t0 = (i0 < NB) ? totals[i0] : 0;
    const int t1 = (i1 < NB) ? totals[i1] : 0;
    const int pair = t0 + t1;
    s[t] = pair;
    __syncthreads();
    for (int off = 1; off < 1024; off <<= 1) {
        int v = (t >= off) ? s[t - off] : 0;
        __syncthreads();
        s[t] += v;
        __syncthreads();
    }
    const int excl = s[t] - pair;
    base[i0] = excl;
    base[i1] = excl + t0;
    if (t == 1023) base[NBH] = E;
}

// ---------------------------------------------------------------------------
// k_scatter3: single pass, no global atomics. blockIdx.y = relation.
// ---------------------------------------------------------------------------
__global__ __launch_bounds__(BTH) void k_scatter3(
    const int* __restrict__ s0p, const int* __restrict__ s1p,
    const int* __restrict__ s2p,
    const int* __restrict__ d0p, const int* __restrict__ d1p,
    const int* __restrict__ d2p,
    int E, int NB,
    const int* __restrict__ hist3, const int* __restrict__ base3,
    int* __restrict__ rs3)
{
    __shared__ int cur[NBH];
    const int rel = blockIdx.y, b = blockIdx.x, tid = threadIdx.x;
    const int* src = (rel == 0) ? s0p : (rel == 1 ? s1p : s2p);
    const int* dst = (rel == 0) ? d0p : (rel == 1 ? d1p : d2p);
    const int* hist_blk = hist3 + (size_t)rel * NBLK * NBH;
    const int* base = base3 + rel * BROW;
    int* rs = rs3 + (size_t)rel * E;

    for (int i = tid; i < NB; i += BTH)
        cur[i] = base[i] + hist_blk[b * NBH + i];
    __syncthreads();
    const int chunk = (E + NBLK - 1) / NBLK;
    const int eb = b * chunk, ee = min(E, eb + chunk);
    for (int i = eb + tid; i < ee; i += BTH) {
        const int d = dst[i];
        const int bkt = d >> BSH;
        const int pos = atomicAdd(&cur[bkt], 1);          // LDS atomic
        rs[pos] = (src[i] << BSH) | (d & (NPB - 1));
    }
}

// ---------------------------------------------------------------------------
// k_gather: one block per (relation, bucket). 4-edge ILP; xr window in LDS.
// Epilogue folds self-loop + bias + LeakyReLU(0.1), writes xout.
// ---------------------------------------------------------------------------
#define EDGE_BODY(XS, XS4, DL)                                                \
    {                                                                         \
        const float* xr = &sxr[(DL) * 5];                                     \
        float t, lg = 0.f;                                                    \
        t = XS.x + xr[0]; t = (t >= 0.f) ? t : 0.2f * t; lg += t * a0;        \
        t = XS.y + xr[1]; t = (t >= 0.f) ? t : 0.2f * t; lg += t * a1;        \
        t = XS.z + xr[2]; t = (t >= 0.f) ? t : 0.2f * t; lg += t * a2;        \
        t = XS.w + xr[3]; t = (t >= 0.f) ? t : 0.2f * t; lg += t * a3;        \
        t = XS4  + xr[4]; t = (t >= 0.f) ? t : 0.2f * t; lg += t * a4;        \
        const float w = __expf(lg);                                           \
        atomicAdd(&acc[DL][0], w * XS.x);                                     \
        atomicAdd(&acc[DL][1], w * XS.y);                                     \
        atomicAdd(&acc[DL][2], w * XS.z);                                     \
        atomicAdd(&acc[DL][3], w * XS.w);                                     \
        atomicAdd(&acc[DL][4], w * XS4);                                      \
        atomicAdd(&acc[DL][5], w);                                            \
    }

template <int NREL>
__global__ __launch_bounds__(256) void k_gather(
    const int* __restrict__ rs3, const int* __restrict__ base3,
    const float* __restrict__ xl8a, const float* __restrict__ xr5a,
    const float* __restrict__ at0, const float* __restrict__ at1,
    const float* __restrict__ at2,
    const float* __restrict__ bi0, const float* __restrict__ bi1,
    const float* __restrict__ bi2,
    float* __restrict__ xouta, int n, int E)
{
    __shared__ float acc[NPB][6];
    __shared__ float sxr[NPB * 5];

    const int bx  = blockIdx.x;
    const int rel = (NREL == 1) ? 0 : bx % NREL;
    const int bkt = (NREL == 1) ? bx : bx / NREL;

    const int*   rs   = rs3 + (size_t)rel * E;
    const int*   base = base3 + rel * BROW;
    const float* xl8  = xl8a + (size_t)rel * 8 * n;
    const float* xr5  = xr5a + (size_t)rel * 5 * n;
    const float* att  = (rel == 0) ? at0 : (rel == 1 ? at1 : at2);
    const float* bias = (rel == 0) ? bi0 : (rel == 1 ? bi1 : bi2);
    float*       xout = xouta + (size_t)rel * 5 * n;

    const int tid = threadIdx.x;
    const int node0 = bkt << BSH;
    const int nn = min(NPB, n - node0);

    for (int i = tid; i < NPB * 6; i += 256) ((float*)acc)[i] = 0.f;
    for (int i = tid; i < nn * 5; i += 256) sxr[i] = xr5[(size_t)node0 * 5 + i];
    __syncthreads();

    const float a0 = att[0], a1 = att[1], a2 = att[2], a3 = att[3], a4 = att[4];
    const int eb = base[bkt], ee = base[bkt + 1];

    int i = eb + tid;
    for (; i + 768 < ee; i += 1024) {
        const int v0 = rs[i], v1 = rs[i + 256], v2 = rs[i + 512], v3 = rs[i + 768];
        const int s0 = v0 >> BSH, s1 = v1 >> BSH, s2 = v2 >> BSH, s3 = v3 >> BSH;
        const int e0 = v0 & (NPB - 1), e1 = v1 & (NPB - 1),
                  e2 = v2 & (NPB - 1), e3 = v3 & (NPB - 1);
        // issue all 8 gather loads before any use (4x lines in flight)
        const float4 xa = *(const float4*)(xl8 + (size_t)s0 * 8);
        const float4 xb = *(const float4*)(xl8 + (size_t)s1 * 8);
        const float4 xc = *(const float4*)(xl8 + (size_t)s2 * 8);
        const float4 xd = *(const float4*)(xl8 + (size_t)s3 * 8);
        const float xa4 = xl8[(size_t)s0 * 8 + 4];
        const float xb4 = xl8[(size_t)s1 * 8 + 4];
        const float xc4 = xl8[(size_t)s2 * 8 + 4];
        const float xd4 = xl8[(size_t)s3 * 8 + 4];
        EDGE_BODY(xa, xa4, e0)
        EDGE_BODY(xb, xb4, e1)
        EDGE_BODY(xc, xc4, e2)
        EDGE_BODY(xd, xd4, e3)
    }
    for (; i < ee; i += 256) {
        const int v = rs[i];
        const int s = v >> BSH;
        const int dl = v & (NPB - 1);
        const float4 xs = *(const float4*)(xl8 + (size_t)s * 8);
        const float xs4 = xl8[(size_t)s * 8 + 4];
        EDGE_BODY(xs, xs4, dl)
    }
    __syncthreads();

    const float b0 = bias[0], b1 = bias[1], b2 = bias[2], b3 = bias[3], b4 = bias[4];
    for (int l = tid; l < nn; l += 256) {
        const int node = node0 + l;
        const size_t s8 = (size_t)node * 8;
        const float4 xs = *(const float4*)(xl8 + s8);
        const float  xs4 = xl8[s8 + 4];
        const float* xr = &sxr[l * 5];

        float t, lg = 0.f;                    // self-loop logit
        t = xs.x + xr[0]; t = (t >= 0.f) ? t : 0.2f * t; lg += t * a0;
        t = xs.y + xr[1]; t = (t >= 0.f) ? t : 0.2f * t; lg += t * a1;
        t = xs.z + xr[2]; t = (t >= 0.f) ? t : 0.2f * t; lg += t * a2;
        t = xs.w + xr[3]; t = (t >= 0.f) ? t : 0.2f * t; lg += t * a3;
        t = xs4  + xr[4]; t = (t >= 0.f) ? t : 0.2f * t; lg += t * a4;
        const float w = __expf(lg);

        const size_t d5 = (size_t)node * 5;
        const float inv = 1.0f / (acc[l][5] + w);
        float v;
        v = (acc[l][0] + w * xs.x) * inv + b0; xout[d5 + 0] = (v >= 0.f) ? v : 0.1f * v;
        v = (acc[l][1] + w * xs.y) * inv + b1; xout[d5 + 1] = (v >= 0.f) ? v : 0.1f * v;
        v = (acc[l][2] + w * xs.z) * inv + b2; xout[d5 + 2] = (v >= 0.f) ? v : 0.1f * v;
        v = (acc[l][3] + w * xs.w) * inv + b3; xout[d5 + 3] = (v >= 0.f) ? v : 0.1f * v;
        v = (acc[l][4] + w * xs4 ) * inv + b4; xout[d5 + 4] = (v >= 0.f) ? v : 0.1f * v;
    }
}

// ---------------------------------------------------------------------------
// k_mlp: fused projection + classifier.
// ---------------------------------------------------------------------------
__global__ __launch_bounds__(256) void k_mlp(
    const float* __restrict__ xp, const float* __restrict__ xs,
    const float* __restrict__ xv,
    const float* __restrict__ Wp1, const float* __restrict__ bp1,
    const float* __restrict__ Wp2, const float* __restrict__ bp2,
    const float* __restrict__ Wc1, const float* __restrict__ bc1,
    const float* __restrict__ Wc2, const float* __restrict__ bc2,
    float* __restrict__ out, int n)
{
    __shared__ float sW[257];
    const int tid = threadIdx.x;
    if (tid < 150) sW[tid] = Wp1[tid];
    if (tid < 10)  sW[150 + tid] = bp1[tid];
    if (tid < 50)  sW[160 + tid] = Wp2[tid];
    if (tid < 5)   sW[210 + tid] = bp2[tid];
    if (tid < 25)  sW[215 + tid] = Wc1[tid];
    if (tid < 5)   sW[240 + tid] = bc1[tid];
    if (tid < 10)  sW[245 + tid] = Wc2[tid];
    if (tid < 2)   sW[255 + tid] = bc2[tid];
    __syncthreads();

    const int node = blockIdx.x * 256 + tid;
    if (node >= n) return;
    const size_t n5 = (size_t)node * KOUT;

    float h[15];
#pragma unroll
    for (int k = 0; k < 5; ++k) {
        h[k]      = xp[n5 + k];
        h[5 + k]  = xs[n5 + k];
        h[10 + k] = xv[n5 + k];
    }

    float t1[10];
#pragma unroll
    for (int o = 0; o < 10; ++o) {
        float a = sW[150 + o];
#pragma unroll
        for (int i = 0; i < 15; ++i) a += h[i] * sW[i * 10 + o];
        t1[o] = (a >= 0.f) ? a : 0.1f * a;
    }

    float t2[5];
#pragma unroll
    for (int o = 0; o < 5; ++o) {
        float a = sW[210 + o];
#pragma unroll
        for (int i = 0; i < 10; ++i) a += t1[i] * sW[160 + i * 5 + o];
        t2[o] = a;
    }

    float t3[5];
#pragma unroll
    for (int o = 0; o < 5; ++o) {
        float a = sW[240 + o];
#pragma unroll
        for (int i = 0; i < 5; ++i) a += t2[i] * sW[215 + i * 5 + o];
        t3[o] = (a >= 0.f) ? a : 0.1f * a;
    }

    float o0 = sW[255], o1 = sW[256];
#pragma unroll
    for (int i = 0; i < 5; ++i) {
        o0 += t3[i] * sW[245 + i * 2 + 0];
        o1 += t3[i] * sW[245 + i * 2 + 1];
    }
    out[(size_t)node * 2 + 0] = o0;
    out[(size_t)node * 2 + 1] = o1;
}

// ---------------------------------------------------------------------------
extern "C" void kernel_launch(void* const* d_in, const int* in_sizes, int n_in,
                              void* d_out, int out_size, void* d_ws, size_t ws_size,
                              hipStream_t stream)
{
    const float* x = (const float*)d_in[0];
    const int n = in_sizes[0] / KIN;          // 1,000,000
    const int E = in_sizes[1] / 2;            // 8,000,000
    const int NB = (n + NPB - 1) >> BSH;      // 1954 buckets (needs n <= 2^20)

    const int* ei[3] = { (const int*)d_in[1], (const int*)d_in[2], (const int*)d_in[3] };
    const float *Wl[3], *Wr[3], *att[3], *bias[3];
    for (int r = 0; r < 3; ++r) {
        const int base = 4 + r * 4;
        Wl[r]   = (const float*)d_in[base + 0];
        Wr[r]   = (const float*)d_in[base + 1];
        att[r]  = (const float*)d_in[base + 2];
        bias[r] = (const float*)d_in[base + 3];
    }
    const float* Wp1 = (const float*)d_in[16];
    const float* bp1 = (const float*)d_in[17];
    const float* Wp2 = (const float*)d_in[18];
    const float* bp2 = (const float*)d_in[19];
    const float* Wc1 = (const float*)d_in[20];
    const float* bc1 = (const float*)d_in[21];
    const float* Wc2 = (const float*)d_in[22];
    const float* bc2 = (const float*)d_in[23];

    // Fused layout A (~313MB): xout[15n] | xl8[3][8n] | xr5[3][5n] |
    //   rs3[3E] | totals3[3*NBH] | base3[3*BROW]
    // Fallback layout B (~144MB): xout[15n] | xl8[8n] | xr5[5n] |
    //   rs[E] | totals[NBH] | base[BROW]
    // hist3 (12.6MB / 4.2MB) overlays xout[10n..15n) (dead until last gather).
    const size_t intsA = (size_t)3 * E + 3 * NBH + 3 * BROW;
    const size_t need_A = ((size_t)54 * n + intsA) * 4;
    const bool fused = ws_size >= need_A;

    float* ws   = (float*)d_ws;
    float* xout = ws;
    float* xl8  = ws + (size_t)15 * n;
    float* xr5  = xl8 + (fused ? (size_t)24 * n : (size_t)8 * n);
    int*   rs3  = (int*)(xr5 + (fused ? (size_t)15 * n : (size_t)5 * n));
    int*   totals3 = rs3 + (fused ? (size_t)3 * E : (size_t)E);
    int*   base3   = totals3 + (fused ? 3 * NBH : NBH);
    int*   hist3   = (int*)(xout + (size_t)10 * n);   // overlay on xv slice

    const int nb_node = (n + 255) / 256;
    const int nb_cols = (NB + 255) / 256;

    if (fused) {
        k_node3<<<nb_node, 256, 0, stream>>>(x, Wl[0], Wr[0], Wl[1], Wr[1],
                                             Wl[2], Wr[2], xl8, xr5, n);
        k_hist3   <<<dim3(NBLK, 3),    BTH,  0, stream>>>(ei[0] + E, ei[1] + E,
                                                          ei[2] + E, E, NB, hist3);
        k_sumoffs3<<<dim3(nb_cols, 3), 256,  0, stream>>>(hist3, NB, totals3);
        k_scan3   <<<3,                1024, 0, stream>>>(totals3, E, NB, base3);
        k_scatter3<<<dim3(NBLK, 3),    BTH,  0, stream>>>(
            ei[0], ei[1], ei[2], ei[0] + E, ei[1] + E, ei[2] + E,
            E, NB, hist3, base3, rs3);
        k_gather<3><<<3 * NB, 256, 0, stream>>>(
            rs3, base3, xl8, xr5,
            att[0], att[1], att[2], bias[0], bias[1], bias[2],
            xout, n, E);
    } else {
        for (int r = 0; r < 3; ++r) {
            float* xo = xout + (size_t)r * 5 * n;
            k_node1<<<nb_node, 256, 0, stream>>>(x, Wl[r], Wr[r], xl8, xr5, n);
            k_hist3   <<<dim3(NBLK, 1),    BTH,  0, stream>>>(ei[r] + E, ei[r] + E,
                                                              ei[r] + E, E, NB, hist3);
            k_sumoffs3<<<dim3(nb_cols, 1), 256,  0, stream>>>(hist3, NB, totals3);
            k_scan3   <<<1,                1024, 0, stream>>>(totals3, E, NB, base3);
            k_scatter3<<<dim3(NBLK, 1),    BTH,  0, stream>>>(
                ei[r], ei[r], ei[r], ei[r] + E, ei[r] + E, ei[r] + E,
                E, NB, hist3, base3, rs3);
            k_gather<1><<<NB, 256, 0, stream>>>(
                rs3, base3, xl8, xr5,
                att[r], att[r], att[r], bias[r], bias[r], bias[r],
                xo, n, E);
        }
    }

    k_mlp<<<nb_node, 256, 0, stream>>>(xout, xout + (size_t)5 * n, xout + (size_t)10 * n,
                                       Wp1, bp1, Wp2, bp2, Wc1, bc1, Wc2, bc2,
                                       (float*)d_out, n);
}

// Round 8
// 1376.777 us; speedup vs baseline: 1.6222x; 1.0092x over previous
//
#include <hip/hip_runtime.h>

static constexpr int KIN   = 25;
static constexpr int KOUT  = 5;
static constexpr int NBLK  = 256;       // blocks for hist/scatter
static constexpr int BTH   = 1024;      // threads for hist/scatter
static constexpr int BSH   = 10;        // log2 nodes per dst-bucket
static constexpr int NPB   = 1 << BSH;  // 1024 nodes per bucket
static constexpr int CSH   = 16;        // log2 nodes per src-chunk (64K * 32B = 2MB window)
static constexpr int HROW  = 16000;     // hist/cur row stride & LDS size (>= NB*NCH)
static constexpr int TROW  = 16384;     // totals length (zero-padded)
static constexpr int BROW2 = 16385;     // base row stride (incl. sentinel)

// ---------------------------------------------------------------------------
// k_node1: single-relation transforms (fallback layout).
// ---------------------------------------------------------------------------
__global__ __launch_bounds__(256) void k_node1(
    const float* __restrict__ x,
    const float* __restrict__ Wl, const float* __restrict__ Wr,
    float* __restrict__ xl8, float* __restrict__ xr5, int n)
{
    __shared__ float sWl[KIN * KOUT];
    __shared__ float sWr[KIN * KOUT];
    __shared__ float sx[256 * KIN];

    const int tid = threadIdx.x;
    if (tid < KIN * KOUT) { sWl[tid] = Wl[tid]; sWr[tid] = Wr[tid]; }

    const int base = blockIdx.x * 256;
    const int cnt  = min(256, n - base);
    const size_t xbase = (size_t)base * KIN;
    for (int i = tid; i < cnt * KIN; i += 256) sx[i] = x[xbase + i];
    __syncthreads();

    if (tid >= cnt) return;
    const int node = base + tid;

    float xls[KOUT] = {0.f, 0.f, 0.f, 0.f, 0.f};
    float xrs[KOUT] = {0.f, 0.f, 0.f, 0.f, 0.f};
    const float* xp = &sx[tid * KIN];
#pragma unroll
    for (int i = 0; i < KIN; ++i) {
        const float xv = xp[i];
#pragma unroll
        for (int o = 0; o < KOUT; ++o) {
            xls[o] += xv * sWl[i * KOUT + o];
            xrs[o] += xv * sWr[i * KOUT + o];
        }
    }

    const size_t n8 = (size_t)node * 8;
    float4 v4;
    v4.x = xls[0]; v4.y = xls[1]; v4.z = xls[2]; v4.w = xls[3];
    *(float4*)(xl8 + n8) = v4;
    xl8[n8 + 4] = xls[4];
    const size_t n5 = (size_t)node * 5;
#pragma unroll
    for (int o = 0; o < KOUT; ++o) xr5[n5 + o] = xrs[o];
}

// ---------------------------------------------------------------------------
// k_node3: all three relations in one pass over x.
// ---------------------------------------------------------------------------
__global__ __launch_bounds__(256) void k_node3(
    const float* __restrict__ x,
    const float* __restrict__ Wl0, const float* __restrict__ Wr0,
    const float* __restrict__ Wl1, const float* __restrict__ Wr1,
    const float* __restrict__ Wl2, const float* __restrict__ Wr2,
    float* __restrict__ xl8, float* __restrict__ xr5,  // [3][n][*]
    int n)
{
    __shared__ float sWl[3][KIN * KOUT];
    __shared__ float sWr[3][KIN * KOUT];
    __shared__ float sx[256 * KIN];

    const int tid = threadIdx.x;
    if (tid < KIN * KOUT) {
        sWl[0][tid] = Wl0[tid]; sWr[0][tid] = Wr0[tid];
        sWl[1][tid] = Wl1[tid]; sWr[1][tid] = Wr1[tid];
        sWl[2][tid] = Wl2[tid]; sWr[2][tid] = Wr2[tid];
    }

    const int base = blockIdx.x * 256;
    const int cnt  = min(256, n - base);
    const size_t xbase = (size_t)base * KIN;
    for (int i = tid; i < cnt * KIN; i += 256) sx[i] = x[xbase + i];
    __syncthreads();

    if (tid >= cnt) return;
    const int node = base + tid;

    float xls[3][KOUT] = {};
    float xrs[3][KOUT] = {};
    const float* xp = &sx[tid * KIN];
#pragma unroll
    for (int i = 0; i < KIN; ++i) {
        const float xv = xp[i];
#pragma unroll
        for (int r = 0; r < 3; ++r)
#pragma unroll
            for (int o = 0; o < KOUT; ++o) {
                xls[r][o] += xv * sWl[r][i * KOUT + o];
                xrs[r][o] += xv * sWr[r][i * KOUT + o];
            }
    }

#pragma unroll
    for (int r = 0; r < 3; ++r) {
        const size_t n8 = (size_t)r * n * 8 + (size_t)node * 8;
        float4 v4;
        v4.x = xls[r][0]; v4.y = xls[r][1]; v4.z = xls[r][2]; v4.w = xls[r][3];
        *(float4*)(xl8 + n8) = v4;
        xl8[n8 + 4] = xls[r][4];
        const size_t n5 = (size_t)r * n * 5 + (size_t)node * 5;
#pragma unroll
        for (int o = 0; o < KOUT; ++o) xr5[n5 + o] = xrs[r][o];
    }
}

// ---------------------------------------------------------------------------
// k_hist2: per-block histogram over 2-level key = dst_bucket*NCH + src_chunk.
// ---------------------------------------------------------------------------
__global__ __launch_bounds__(BTH) void k_hist2(
    const int* __restrict__ src, const int* __restrict__ dst,
    int E, int NB2, int NCH, int* __restrict__ hist_blk)
{
    __shared__ int h[HROW];
    const int b = blockIdx.x, tid = threadIdx.x;
    for (int i = tid; i < NB2; i += BTH) h[i] = 0;
    __syncthreads();
    const int chunk = (E + NBLK - 1) / NBLK;
    const int eb = b * chunk, ee = min(E, eb + chunk);
    for (int i = eb + tid; i < ee; i += BTH) {
        const int key = (dst[i] >> BSH) * NCH + (src[i] >> CSH);
        atomicAdd(&h[key], 1);
    }
    __syncthreads();
    for (int i = tid; i < NB2; i += BTH) hist_blk[b * HROW + i] = h[i];
}

// ---------------------------------------------------------------------------
// k_sumoffs2: per key, turn hist rows in place into exclusive per-block
// offsets; write totals (zero-padded to TROW).
// ---------------------------------------------------------------------------
__global__ __launch_bounds__(256) void k_sumoffs2(
    int* __restrict__ hist_blk, int NB2, int* __restrict__ totals)
{
    const int i = blockIdx.x * 256 + threadIdx.x;
    if (i >= TROW) return;
    if (i >= NB2) { totals[i] = 0; return; }
    int s = 0;
    for (int b = 0; b < NBLK; ++b) {
        const int t = hist_blk[b * HROW + i];
        hist_blk[b * HROW + i] = s;
        s += t;
    }
    totals[i] = s;
}

// ---------------------------------------------------------------------------
// k_scan16: one block, exclusive scan of totals[0..TROW) -> base[0..TROW].
// 16 elems/thread.
// ---------------------------------------------------------------------------
__global__ __launch_bounds__(1024) void k_scan16(
    const int* __restrict__ totals, int* __restrict__ base)
{
    __shared__ int s[1024];
    const int t = threadIdx.x;
    int loc[16];
    int sum = 0;
#pragma unroll
    for (int j = 0; j < 16; ++j) { loc[j] = totals[t * 16 + j]; sum += loc[j]; }
    s[t] = sum;
    __syncthreads();
    for (int off = 1; off < 1024; off <<= 1) {
        int v = (t >= off) ? s[t - off] : 0;
        __syncthreads();
        s[t] += v;
        __syncthreads();
    }
    int run = s[t] - sum;
#pragma unroll
    for (int j = 0; j < 16; ++j) { base[t * 16 + j] = run; run += loc[j]; }
    if (t == 1023) base[TROW] = run;   // == E
}

// ---------------------------------------------------------------------------
// k_scatter2: single pass, no global atomics. rs = (src << BSH) | dst_local;
// within each dst-bucket segment, edges land sorted by src-chunk.
// ---------------------------------------------------------------------------
__global__ __launch_bounds__(BTH) void k_scatter2(
    const int* __restrict__ src, const int* __restrict__ dst,
    int E, int NB2, int NCH,
    const int* __restrict__ hist_blk, const int* __restrict__ base,
    int* __restrict__ rs)
{
    __shared__ int cur[HROW];
    const int b = blockIdx.x, tid = threadIdx.x;
    for (int i = tid; i < NB2; i += BTH)
        cur[i] = base[i] + hist_blk[b * HROW + i];
    __syncthreads();
    const int chunk = (E + NBLK - 1) / NBLK;
    const int eb = b * chunk, ee = min(E, eb + chunk);
    for (int i = eb + tid; i < ee; i += BTH) {
        const int d = dst[i];
        const int sc = src[i];
        const int key = (d >> BSH) * NCH + (sc >> CSH);
        const int pos = atomicAdd(&cur[key], 1);          // LDS atomic
        rs[pos] = (sc << BSH) | (d & (NPB - 1));
    }
}

// ---------------------------------------------------------------------------
// k_gather: one block per dst-bucket; processes the 3 relations sequentially
// (one relation's 2MB src window hot at a time -> L2-resident). Edges within
// a bucket arrive sorted by src-chunk. 4-edge ILP. Epilogue folds self-loop
// + bias + LeakyReLU(0.1).
// ---------------------------------------------------------------------------
#define EDGE_BODY(XS, XS4, DL)                                                \
    {                                                                         \
        const size_t dq = (size_t)(node0 + (DL)) * 5;                         \
        float t, lg = 0.f;                                                    \
        t = XS.x + xr5[dq + 0]; t = (t >= 0.f) ? t : 0.2f * t; lg += t * a0;  \
        t = XS.y + xr5[dq + 1]; t = (t >= 0.f) ? t : 0.2f * t; lg += t * a1;  \
        t = XS.z + xr5[dq + 2]; t = (t >= 0.f) ? t : 0.2f * t; lg += t * a2;  \
        t = XS.w + xr5[dq + 3]; t = (t >= 0.f) ? t : 0.2f * t; lg += t * a3;  \
        t = XS4  + xr5[dq + 4]; t = (t >= 0.f) ? t : 0.2f * t; lg += t * a4;  \
        const float w = __expf(lg);                                           \
        atomicAdd(&acc[DL][0], w * XS.x);                                     \
        atomicAdd(&acc[DL][1], w * XS.y);                                     \
        atomicAdd(&acc[DL][2], w * XS.z);                                     \
        atomicAdd(&acc[DL][3], w * XS.w);                                     \
        atomicAdd(&acc[DL][4], w * XS4);                                      \
        atomicAdd(&acc[DL][5], w);                                            \
    }

template <int NREL>
__global__ __launch_bounds__(256) void k_gather(
    const int* __restrict__ rs3, const int* __restrict__ base3,
    const float* __restrict__ xl8a, const float* __restrict__ xr5a,
    const float* __restrict__ at0, const float* __restrict__ at1,
    const float* __restrict__ at2,
    const float* __restrict__ bi0, const float* __restrict__ bi1,
    const float* __restrict__ bi2,
    float* __restrict__ xouta, int n, int E, int NCH)
{
    __shared__ float acc[NPB][6];

    const int bkt = blockIdx.x;
    const int tid = threadIdx.x;
    const int node0 = bkt << BSH;
    const int nn = min(NPB, n - node0);

    for (int rel = 0; rel < NREL; ++rel) {
        const int*   rs   = rs3 + (size_t)rel * E;
        const int*   base = base3 + (size_t)rel * BROW2;
        const float* xl8  = xl8a + (size_t)rel * 8 * n;
        const float* xr5  = xr5a + (size_t)rel * 5 * n;
        const float* att  = (rel == 0) ? at0 : (rel == 1 ? at1 : at2);
        const float* bias = (rel == 0) ? bi0 : (rel == 1 ? bi1 : bi2);
        float*       xout = xouta + (size_t)rel * 5 * n;

        for (int i = tid; i < NPB * 6; i += 256) ((float*)acc)[i] = 0.f;
        __syncthreads();

        const float a0 = att[0], a1 = att[1], a2 = att[2], a3 = att[3], a4 = att[4];
        const int eb = base[bkt * NCH], ee = base[(bkt + 1) * NCH];

        int i = eb + tid;
        for (; i + 768 < ee; i += 1024) {
            const int v0 = rs[i], v1 = rs[i + 256], v2 = rs[i + 512], v3 = rs[i + 768];
            const int s0 = v0 >> BSH, s1 = v1 >> BSH, s2 = v2 >> BSH, s3 = v3 >> BSH;
            const int e0 = v0 & (NPB - 1), e1 = v1 & (NPB - 1),
                      e2 = v2 & (NPB - 1), e3 = v3 & (NPB - 1);
            const float4 xa = *(const float4*)(xl8 + (size_t)s0 * 8);
            const float4 xb = *(const float4*)(xl8 + (size_t)s1 * 8);
            const float4 xc = *(const float4*)(xl8 + (size_t)s2 * 8);
            const float4 xd = *(const float4*)(xl8 + (size_t)s3 * 8);
            const float xa4 = xl8[(size_t)s0 * 8 + 4];
            const float xb4 = xl8[(size_t)s1 * 8 + 4];
            const float xc4 = xl8[(size_t)s2 * 8 + 4];
            const float xd4 = xl8[(size_t)s3 * 8 + 4];
            EDGE_BODY(xa, xa4, e0)
            EDGE_BODY(xb, xb4, e1)
            EDGE_BODY(xc, xc4, e2)
            EDGE_BODY(xd, xd4, e3)
        }
        for (; i < ee; i += 256) {
            const int v = rs[i];
            const int s = v >> BSH;
            const int dl = v & (NPB - 1);
            const float4 xs = *(const float4*)(xl8 + (size_t)s * 8);
            const float xs4 = xl8[(size_t)s * 8 + 4];
            EDGE_BODY(xs, xs4, dl)
        }
        __syncthreads();

        const float b0 = bias[0], b1 = bias[1], b2 = bias[2], b3 = bias[3], b4 = bias[4];
        for (int l = tid; l < nn; l += 256) {
            const int node = node0 + l;
            const size_t s8 = (size_t)node * 8;
            const float4 xs = *(const float4*)(xl8 + s8);
            const float  xs4 = xl8[s8 + 4];
            const size_t dq = (size_t)node * 5;

            float t, lg = 0.f;                    // self-loop logit
            t = xs.x + xr5[dq + 0]; t = (t >= 0.f) ? t : 0.2f * t; lg += t * a0;
            t = xs.y + xr5[dq + 1]; t = (t >= 0.f) ? t : 0.2f * t; lg += t * a1;
            t = xs.z + xr5[dq + 2]; t = (t >= 0.f) ? t : 0.2f * t; lg += t * a2;
            t = xs.w + xr5[dq + 3]; t = (t >= 0.f) ? t : 0.2f * t; lg += t * a3;
            t = xs4  + xr5[dq + 4]; t = (t >= 0.f) ? t : 0.2f * t; lg += t * a4;
            const float w = __expf(lg);

            const float inv = 1.0f / (acc[l][5] + w);
            float v;
            v = (acc[l][0] + w * xs.x) * inv + b0; xout[dq + 0] = (v >= 0.f) ? v : 0.1f * v;
            v = (acc[l][1] + w * xs.y) * inv + b1; xout[dq + 1] = (v >= 0.f) ? v : 0.1f * v;
            v = (acc[l][2] + w * xs.z) * inv + b2; xout[dq + 2] = (v >= 0.f) ? v : 0.1f * v;
            v = (acc[l][3] + w * xs.w) * inv + b3; xout[dq + 3] = (v >= 0.f) ? v : 0.1f * v;
            v = (acc[l][4] + w * xs4 ) * inv + b4; xout[dq + 4] = (v >= 0.f) ? v : 0.1f * v;
        }
        __syncthreads();
    }
}

// ---------------------------------------------------------------------------
// k_mlp: fused projection + classifier.
// ---------------------------------------------------------------------------
__global__ __launch_bounds__(256) void k_mlp(
    const float* __restrict__ xp, const float* __restrict__ xs,
    const float* __restrict__ xv,
    const float* __restrict__ Wp1, const float* __restrict__ bp1,
    const float* __restrict__ Wp2, const float* __restrict__ bp2,
    const float* __restrict__ Wc1, const float* __restrict__ bc1,
    const float* __restrict__ Wc2, const float* __restrict__ bc2,
    float* __restrict__ out, int n)
{
    __shared__ float sW[257];
    const int tid = threadIdx.x;
    if (tid < 150) sW[tid] = Wp1[tid];
    if (tid < 10)  sW[150 + tid] = bp1[tid];
    if (tid < 50)  sW[160 + tid] = Wp2[tid];
    if (tid < 5)   sW[210 + tid] = bp2[tid];
    if (tid < 25)  sW[215 + tid] = Wc1[tid];
    if (tid < 5)   sW[240 + tid] = bc1[tid];
    if (tid < 10)  sW[245 + tid] = Wc2[tid];
    if (tid < 2)   sW[255 + tid] = bc2[tid];
    __syncthreads();

    const int node = blockIdx.x * 256 + tid;
    if (node >= n) return;
    const size_t n5 = (size_t)node * KOUT;

    float h[15];
#pragma unroll
    for (int k = 0; k < 5; ++k) {
        h[k]      = xp[n5 + k];
        h[5 + k]  = xs[n5 + k];
        h[10 + k] = xv[n5 + k];
    }

    float t1[10];
#pragma unroll
    for (int o = 0; o < 10; ++o) {
        float a = sW[150 + o];
#pragma unroll
        for (int i = 0; i < 15; ++i) a += h[i] * sW[i * 10 + o];
        t1[o] = (a >= 0.f) ? a : 0.1f * a;
    }

    float t2[5];
#pragma unroll
    for (int o = 0; o < 5; ++o) {
        float a = sW[210 + o];
#pragma unroll
        for (int i = 0; i < 10; ++i) a += t1[i] * sW[160 + i * 5 + o];
        t2[o] = a;
    }

    float t3[5];
#pragma unroll
    for (int o = 0; o < 5; ++o) {
        float a = sW[240 + o];
#pragma unroll
        for (int i = 0; i < 5; ++i) a += t2[i] * sW[215 + i * 5 + o];
        t3[o] = (a >= 0.f) ? a : 0.1f * a;
    }

    float o0 = sW[255], o1 = sW[256];
#pragma unroll
    for (int i = 0; i < 5; ++i) {
        o0 += t3[i] * sW[245 + i * 2 + 0];
        o1 += t3[i] * sW[245 + i * 2 + 1];
    }
    out[(size_t)node * 2 + 0] = o0;
    out[(size_t)node * 2 + 1] = o1;
}

// ---------------------------------------------------------------------------
extern "C" void kernel_launch(void* const* d_in, const int* in_sizes, int n_in,
                              void* d_out, int out_size, void* d_ws, size_t ws_size,
                              hipStream_t stream)
{
    const float* x = (const float*)d_in[0];
    const int n = in_sizes[0] / KIN;              // 1,000,000
    const int E = in_sizes[1] / 2;                // 8,000,000
    const int NB  = (n + NPB - 1) >> BSH;         // 977 dst-buckets
    const int NCH = (n + (1 << CSH) - 1) >> CSH;  // 16 src-chunks
    const int NB2 = NB * NCH;                     // 15632 keys (<= HROW)

    const int* ei[3] = { (const int*)d_in[1], (const int*)d_in[2], (const int*)d_in[3] };
    const float *Wl[3], *Wr[3], *att[3], *bias[3];
    for (int r = 0; r < 3; ++r) {
        const int base = 4 + r * 4;
        Wl[r]   = (const float*)d_in[base + 0];
        Wr[r]   = (const float*)d_in[base + 1];
        att[r]  = (const float*)d_in[base + 2];
        bias[r] = (const float*)d_in[base + 3];
    }
    const float* Wp1 = (const float*)d_in[16];
    const float* bp1 = (const float*)d_in[17];
    const float* Wp2 = (const float*)d_in[18];
    const float* bp2 = (const float*)d_in[19];
    const float* Wc1 = (const float*)d_in[20];
    const float* bc1 = (const float*)d_in[21];
    const float* Wc2 = (const float*)d_in[22];
    const float* bc2 = (const float*)d_in[23];

    // Fused layout A (~312.5MB): xout[15n] | xl8[3][8n] | xr5[3][5n] |
    //   rs3[3E] | totals[TROW] | base3[3*BROW2]
    // Fallback B (~144.5MB):     xout[15n] | xl8[8n] | xr5[5n] |
    //   rs[E] | totals[TROW] | base[BROW2]
    // hist_blk (NBLK*HROW ints = 16.4MB) overlays xout[10n..15n) (20MB slice,
    // dead until the final gather writes it).
    const size_t intsA = (size_t)3 * E + TROW + (size_t)3 * BROW2;
    const size_t need_A = ((size_t)54 * n + intsA) * 4;
    const bool fused = ws_size >= need_A;

    float* ws   = (float*)d_ws;
    float* xout = ws;
    float* xl8  = ws + (size_t)15 * n;
    float* xr5  = xl8 + (fused ? (size_t)24 * n : (size_t)8 * n);
    int*   rs3  = (int*)(xr5 + (fused ? (size_t)15 * n : (size_t)5 * n));
    int*   totals = rs3 + (fused ? (size_t)3 * E : (size_t)E);
    int*   base3  = totals + TROW;
    int*   hist_blk = (int*)(xout + (size_t)10 * n);   // overlay on xv slice

    const int nb_node = (n + 255) / 256;
    const int nb_sums = (TROW + 255) / 256;

    if (fused) {
        k_node3<<<nb_node, 256, 0, stream>>>(x, Wl[0], Wr[0], Wl[1], Wr[1],
                                             Wl[2], Wr[2], xl8, xr5, n);
        for (int r = 0; r < 3; ++r) {
            int* rs   = rs3 + (size_t)r * E;
            int* base = base3 + (size_t)r * BROW2;
            k_hist2   <<<NBLK,    BTH,  0, stream>>>(ei[r], ei[r] + E, E, NB2, NCH, hist_blk);
            k_sumoffs2<<<nb_sums, 256,  0, stream>>>(hist_blk, NB2, totals);
            k_scan16  <<<1,       1024, 0, stream>>>(totals, base);
            k_scatter2<<<NBLK,    BTH,  0, stream>>>(ei[r], ei[r] + E, E, NB2, NCH,
                                                     hist_blk, base, rs);
        }
        k_gather<3><<<NB, 256, 0, stream>>>(
            rs3, base3, xl8, xr5,
            att[0], att[1], att[2], bias[0], bias[1], bias[2],
            xout, n, E, NCH);
    } else {
        for (int r = 0; r < 3; ++r) {
            float* xo = xout + (size_t)r * 5 * n;
            k_node1<<<nb_node, 256, 0, stream>>>(x, Wl[r], Wr[r], xl8, xr5, n);
            k_hist2   <<<NBLK,    BTH,  0, stream>>>(ei[r], ei[r] + E, E, NB2, NCH, hist_blk);
            k_sumoffs2<<<nb_sums, 256,  0, stream>>>(hist_blk, NB2, totals);
            k_scan16  <<<1,       1024, 0, stream>>>(totals, base3);
            k_scatter2<<<NBLK,    BTH,  0, stream>>>(ei[r], ei[r] + E, E, NB2, NCH,
                                                     hist_blk, base3, rs3);
            k_gather<1><<<NB, 256, 0, stream>>>(
                rs3, base3, xl8, xr5,
                att[r], att[r], att[r], bias[r], bias[r], bias[r],
                xo, n, E, NCH);
        }
    }

    k_mlp<<<nb_node, 256, 0, stream>>>(xout, xout + (size_t)5 * n, xout + (size_t)10 * n,
                                       Wp1, bp1, Wp2, bp2, Wc1, bc1, Wc2, bc2,
                                       (float*)d_out, n);
}